// Round 5
// baseline (1370.808 us; speedup 1.0000x reference)
//
#include <hip/hip_runtime.h>
#include <math.h>

#define DEVI __device__ __forceinline__

typedef __attribute__((ext_vector_type(8))) short short8;
typedef __attribute__((ext_vector_type(4))) float f32x4;

DEVI float bf2f(short u){ unsigned v = ((unsigned)(unsigned short)u) << 16; return __builtin_bit_cast(float, v); }
DEVI short f2bs(float f){
  unsigned x = __builtin_bit_cast(unsigned, f);
  unsigned r = (x + 0x7fffu + ((x >> 16) & 1u)) >> 16;
  return (short)(unsigned short)r;
}
DEVI float clampf(float x, float lo, float hi){ return fminf(fmaxf(x, lo), hi); }
DEVI float n2nf(float x){
  if (x != x) return 0.f;
  if (x == INFINITY) return 1.f;
  if (x == -INFINITY) return -1.f;
  return x;
}
DEVI float sigmoidf(float x){ return 1.f/(1.f+expf(-x)); }
DEVI f32x4 mfma16(short8 a, short8 b, f32x4 c){ return __builtin_amdgcn_mfma_f32_16x16x32_bf16(a,b,c,0,0,0); }

DEVI float blkSum(float v, float* s4, int tid){
  #pragma unroll
  for (int o=32;o;o>>=1) v += __shfl_xor(v,o);
  __syncthreads();
  if ((tid&63)==0) s4[tid>>6] = v;
  __syncthreads();
  return s4[0]+s4[1]+s4[2]+s4[3];
}

// ---------------- utility kernels ----------------
__global__ void k_convert(const float* __restrict__ s, short* __restrict__ d, int n){
  int i = blockIdx.x*256 + threadIdx.x;
  if (i < n) d[i] = f2bs(s[i]);
}

__global__ void k_prep_gwp(const float* __restrict__ gw, const float* __restrict__ gb, short* __restrict__ gwp){
  int i = blockIdx.x*256 + threadIdx.x;   // 0..16383
  int d = i >> 6, c = i & 63;
  float v = (c < 39) ? gw[d*39 + c] : (c == 39 ? gb[d] : 0.f);
  gwp[i] = f2bs(v);
}

__global__ void k_init(const float* __restrict__ slots_p, const float* __restrict__ Sp0, const float* __restrict__ Ss0,
                       float* __restrict__ slots, float* __restrict__ sp, float* __restrict__ ssb){
  int bs = blockIdx.x, t = threadIdx.x, s = bs & 7;
  slots[bs*256+t] = slots_p[s*256+t];
  if (t < 3){ sp[bs*3+t] = Sp0[s*3+t]; ssb[bs*3+t] = Ss0[s*3+t]; }
}

__global__ __launch_bounds__(256) void k_ln768(const float* __restrict__ in, const float* __restrict__ g,
                                               const float* __restrict__ bt, short* __restrict__ out){
  int r = blockIdx.x, t = threadIdx.x;
  __shared__ float s4[4];
  const float* row = in + (size_t)r*768;
  float x0=row[t], x1=row[256+t], x2=row[512+t];
  float m = blkSum(x0+x1+x2, s4, t) * (1.f/768.f);
  float d0=x0-m, d1=x1-m, d2=x2-m;
  float var = blkSum(d0*d0+d1*d1+d2*d2, s4, t) * (1.f/768.f);
  float rstd = 1.f/sqrtf(var + 1e-5f);
  short* orow = out + (size_t)r*768;
  orow[t]     = f2bs(d0*rstd*g[t]     + bt[t]);
  orow[256+t] = f2bs(d1*rstd*g[256+t] + bt[256+t]);
  orow[512+t] = f2bs(d2*rstd*g[512+t] + bt[512+t]);
}

__global__ __launch_bounds__(256) void k_ln256(const float* __restrict__ in, const float* __restrict__ g,
                                               const float* __restrict__ bt, short* __restrict__ out){
  int r = blockIdx.x, t = threadIdx.x;
  __shared__ float s4[4];
  float x = in[(size_t)r*256 + t];
  float m = blkSum(x, s4, t) * (1.f/256.f);
  float d = x - m;
  float var = blkSum(d*d, s4, t) * (1.f/256.f);
  out[(size_t)r*256 + t] = f2bs(d*(1.f/sqrtf(var+1e-5f))*g[t] + bt[t]);
}

// ---------------- generic MFMA GEMM (single instantiation, runtime KT/flags) ----------------
// out[M x Ncols] = A[M x KT] @ W[Ncols x KT]^T (+bias)(+relu)
// flags: 1=bias, 2=relu, 4=bf16out
__global__ __launch_bounds__(256) void k_gemm(const short* __restrict__ A, const short* __restrict__ W,
                                              const float* __restrict__ bias, void* __restrict__ outp,
                                              int ldo, int KT, int flags){
  const int w = threadIdx.x>>6, l = threadIdx.x&63, l15 = l&15, l4 = l>>4;
  const int row0 = blockIdx.x*64 + w*16;
  const int col0 = blockIdx.y*128;
  f32x4 acc[8];
  #pragma unroll
  for (int i=0;i<8;i++) acc[i] = (f32x4)(0.f);
  const short* Ap  = A + (size_t)(row0+l15)*KT + l4*8;
  const short* Wp0 = W + (size_t)(col0+l15)*KT + l4*8;
  #pragma unroll 1
  for (int kk=0; kk<KT/32; ++kk){
    short8 af = *(const short8*)(Ap + kk*32);
    #pragma unroll
    for (int ci=0; ci<8; ++ci){
      short8 bfr = *(const short8*)(Wp0 + (size_t)ci*16*KT + kk*32);
      acc[ci] = mfma16(af, bfr, acc[ci]);
    }
  }
  #pragma unroll
  for (int ci=0; ci<8; ++ci){
    int col = col0 + ci*16 + l15;
    float bv = (flags&1) ? bias[col] : 0.f;
    #pragma unroll
    for (int j=0;j<4;j++){
      int row = row0 + l4*4 + j;
      float v = acc[ci][j] + bv;
      if (flags&2) v = fmaxf(v, 0.f);
      if (flags&4) ((short*)outp)[(size_t)row*ldo + col] = f2bs(v);
      else         ((float*)outp)[(size_t)row*ldo + col] = v;
    }
  }
}

// ---------------- per-iteration small kernel: sn=LN(slots); q=sn@Qw^T; qf2=q@f2w; qb=q.f2b ----------------
__global__ __launch_bounds__(256) void k_qprep(const float* __restrict__ slots,
    const float* __restrict__ ng, const float* __restrict__ nb,
    const float* __restrict__ Qw, const float* __restrict__ f2w, const float* __restrict__ f2b,
    float* __restrict__ qf2, float* __restrict__ qbv){
  int bs = blockIdx.x, t = threadIdx.x;
  __shared__ float sn[256], q[256], s4[4];
  float x = slots[bs*256+t];
  float m = blkSum(x, s4, t)*(1.f/256.f);
  float d = x - m;
  float var = blkSum(d*d, s4, t)*(1.f/256.f);
  sn[t] = d*(1.f/sqrtf(var+1e-5f))*ng[t] + nb[t];
  __syncthreads();
  {
    const float4* qr = (const float4*)(Qw + (size_t)t*256);
    float s = 0.f;
    for (int d4=0; d4<64; ++d4){
      float4 w4 = qr[d4];
      s += sn[d4*4+0]*w4.x + sn[d4*4+1]*w4.y + sn[d4*4+2]*w4.z + sn[d4*4+3]*w4.w;
    }
    q[t] = s;
  }
  __syncthreads();
  {
    float s = 0.f;
    for (int o=0;o<256;o++) s += q[o]*f2w[(size_t)o*256 + t];
    qf2[bs*256+t] = s;
  }
  float tot = blkSum(q[t]*f2b[t], s4, t);
  if (t==0) qbv[bs] = tot;
}

// ---------------- the big fused kernel ----------------
__global__ __launch_bounds__(256) void k_isa_a(
    const float* __restrict__ coords, const float* __restrict__ sp, const float* __restrict__ ssb,
    const short* __restrict__ gwp, const short* __restrict__ kx, const short* __restrict__ vx,
    const short* __restrict__ f1w, const float* __restrict__ f1b,
    const float* __restrict__ qf2, const float* __restrict__ qbv,
    float* __restrict__ dots, short* __restrict__ hv, int npass){
  __shared__ __align__(16) short ffs[64*64];
  __shared__ __align__(16) short abuf[64*256];
  __shared__ float sf1b[256];
  __shared__ float sqf2[256];
  __shared__ float smisc[8];
  const int tid = threadIdx.x;
  const int bs = blockIdx.y;
  const int b  = bs >> 3;
  const int n0 = blockIdx.x * 64;

  sf1b[tid] = f1b[tid];
  sqf2[tid] = qf2[bs*256 + tid];
  if (tid < 3){
    smisc[tid] = sp[bs*3+tid];
    float sv = ssb[bs*3+tid];
    float sa = clampf(sv, 0.3f, 5.f) + 0.1f;
    smisc[4+tid] = 1.f/(sa*5.f + 1e-4f);
  }
  if (tid == 7) smisc[7] = qbv[bs];
  __syncthreads();

  // fourier features into ffs (row n: [rel0..2, sin/cos interleaved (36), 1(bias), 0-pad -> 64])
  {
    const float FRQ[6] = {6.283185307179586f,12.566370614359172f,25.132741228718345f,
                          50.26548245743669f,100.53096491487338f,201.06192982974676f};
    int n  = tid >> 2;
    int cb = (tid & 3) * 16;
    float rel[3];
    #pragma unroll
    for (int i=0;i<3;i++){
      float c = coords[((size_t)(b*2048 + n0 + n))*3 + i];
      rel[i] = clampf((c - smisc[i]) * smisc[4+i], -3.f, 3.f);
    }
    #pragma unroll 1
    for (int cc=0; cc<16; ++cc){
      int c = cb + cc;
      float v;
      if (c < 3) v = rel[c];
      else if (c < 39){
        int q = c-3; int i = q/12; int j = (q%12)>>1;
        float ang = rel[i]*FRQ[j];
        v = (q & 1) ? cosf(ang) : sinf(ang);
      }
      else if (c == 39) v = 1.f;
      else v = 0.f;
      ffs[n*64 + (((c>>3)^(n&7))<<3) + (c&7)] = f2bs(v);
    }
  }
  __syncthreads();

  const int w = tid>>6, l = tid&63, l15 = l&15, l4 = l>>4;
  const int ar = w*16 + l15;           // A-row this lane reads (wave-private)
  f32x4 acc[16];

  #pragma unroll 1
  for (int pass = 0; pass < npass; ++pass){
    // ---- gr GEMM (K=64) ----
    #pragma unroll
    for (int ci=0;ci<16;ci++) acc[ci] = (f32x4)(0.f);
    #pragma unroll 1
    for (int kk=0;kk<2;kk++){
      short8 af = *(const short8*)&ffs[ar*64 + (((kk*4+l4) ^ (ar&7))<<3)];
      #pragma unroll
      for (int ci=0;ci<16;ci++){
        short8 bfr = *(const short8*)&gwp[(size_t)(ci*16+l15)*64 + kk*32 + l4*8];
        acc[ci] = mfma16(af, bfr, acc[ci]);
      }
    }
    // ---- a = (Kx|Vx) + gr  ->  abuf (bf16, swizzled) ----
    {
      const short* src = pass ? vx : kx;
      #pragma unroll
      for (int ci=0;ci<16;ci++){
        #pragma unroll
        for (int j=0;j<4;j++){
          int row = w*16 + l4*4 + j;
          int col = ci*16 + l15;
          float v = acc[ci][j] + bf2f(src[((size_t)(b*2048 + n0 + row))*256 + col]);
          abuf[row*256 + (((col>>3)^(row&7))<<3) + (col&7)] = f2bs(v);
        }
      }
    }
    __syncthreads();
    // ---- f1 GEMM (K=256) ----
    #pragma unroll
    for (int ci=0;ci<16;ci++) acc[ci] = (f32x4)(0.f);
    #pragma unroll 1
    for (int kk=0;kk<8;kk++){
      short8 af = *(const short8*)&abuf[ar*256 + (((kk*4+l4) ^ (ar&7))<<3)];
      #pragma unroll
      for (int ci=0;ci<16;ci++){
        short8 bfr = *(const short8*)&f1w[(size_t)(ci*16+l15)*256 + kk*32 + l4*8];
        acc[ci] = mfma16(af, bfr, acc[ci]);
      }
    }
    if (pass == 0){
      float p0=0.f,p1=0.f,p2=0.f,p3=0.f;
      #pragma unroll
      for (int ci=0;ci<16;ci++){
        int col = ci*16 + l15;
        float qv = sqf2[col], bv = sf1b[col];
        p0 += fmaxf(acc[ci][0]+bv,0.f)*qv;
        p1 += fmaxf(acc[ci][1]+bv,0.f)*qv;
        p2 += fmaxf(acc[ci][2]+bv,0.f)*qv;
        p3 += fmaxf(acc[ci][3]+bv,0.f)*qv;
      }
      #pragma unroll
      for (int o=8;o;o>>=1){
        p0 += __shfl_xor(p0,o); p1 += __shfl_xor(p1,o);
        p2 += __shfl_xor(p2,o); p3 += __shfl_xor(p3,o);
      }
      if (l15 == 0){
        float pj[4] = {p0,p1,p2,p3};
        #pragma unroll
        for (int j=0;j<4;j++){
          int row = w*16 + l4*4 + j;
          float dd = clampf((pj[j] + smisc[7]) * 0.0625f, -30.f, 30.f);
          dots[(size_t)bs*2048 + n0 + row] = dd;
        }
      }
      __syncthreads();
    } else {
      #pragma unroll
      for (int ci=0;ci<16;ci++){
        int col = ci*16 + l15;
        float bv = sf1b[col];
        #pragma unroll
        for (int j=0;j<4;j++){
          int row = w*16 + l4*4 + j;
          hv[((size_t)(bs*2048 + n0 + row))*256 + col] = f2bs(fmaxf(acc[ci][j]+bv,0.f));
        }
      }
    }
  }
}

// ---------------- softmax over s (8 slots) + per-chunk partial sums ----------------
__global__ __launch_bounds__(256) void k_softmax(const float* __restrict__ dots, float* __restrict__ aun,
                                                 float* __restrict__ sump){
  int blk = blockIdx.x;
  int b = blk >> 3, chunk = blk & 7;
  int n = chunk*256 + threadIdx.x;
  float d[8];
  #pragma unroll
  for (int s=0;s<8;s++) d[s] = dots[(size_t)(b*8+s)*2048 + n];
  float m = d[0];
  #pragma unroll
  for (int s=1;s<8;s++) m = fmaxf(m, d[s]);
  float e[8]; float sum = 0.f;
  #pragma unroll
  for (int s=0;s<8;s++){ e[s] = expf(d[s]-m); sum += e[s]; }
  float inv = 1.f/sum;
  __shared__ float red[4][8];
  int wv = threadIdx.x>>6, ln = threadIdx.x&63;
  #pragma unroll
  for (int s=0;s<8;s++){
    float a = e[s]*inv + 1e-8f;
    aun[(size_t)(b*8+s)*2048 + n] = a;
    float v = a;
    #pragma unroll
    for (int o=32;o;o>>=1) v += __shfl_xor(v,o);
    if (ln == 0) red[wv][s] = v;
  }
  __syncthreads();
  if (threadIdx.x < 8){
    int s = threadIdx.x;
    sump[(b*8+s)*8 + chunk] = red[0][s]+red[1][s]+red[2][s]+red[3][s];
  }
}

// ---------------- weighted partial reductions over n ----------------
__global__ __launch_bounds__(256) void k_c1(const float* __restrict__ aun, const short* __restrict__ hv,
    const float* __restrict__ coords, float* __restrict__ hvpart, float* __restrict__ mompart){
  int chunk = blockIdx.x, bs = blockIdx.y, b = bs >> 3;
  int t = threadIdx.x;
  int nb = chunk*256;
  __shared__ float wsm[256];
  wsm[t] = aun[(size_t)bs*2048 + nb + t];
  __syncthreads();
  float acc = 0.f;
  const short* hp = hv + ((size_t)bs*2048 + nb)*256 + t;
  #pragma unroll 4
  for (int n=0;n<256;n++) acc += wsm[n]*bf2f(hp[(size_t)n*256]);
  hvpart[(size_t)(bs*8+chunk)*256 + t] = acc;
  float wv = wsm[t];
  const float* cp = coords + ((size_t)(b*2048) + nb + t)*3;
  float c0=cp[0], c1=cp[1], c2=cp[2];
  float mv[6] = {wv*c0, wv*c1, wv*c2, wv*c0*c0, wv*c1*c1, wv*c2*c2};
  __shared__ float red[4][6];
  int wvx = t>>6, ln = t&63;
  #pragma unroll
  for (int i=0;i<6;i++){
    float v = mv[i];
    #pragma unroll
    for (int o=32;o;o>>=1) v += __shfl_xor(v,o);
    if (ln==0) red[wvx][i] = v;
  }
  __syncthreads();
  if (t<6) mompart[(bs*8+chunk)*6 + t] = red[0][t]+red[1][t]+red[2][t]+red[3][t];
}

// ---------------- final per-(b,s): updates, S_p, S_s, GRU, LN, MLP ----------------
__global__ __launch_bounds__(256) void k_c2(
    const float* __restrict__ hvpart, const float* __restrict__ mompart, const float* __restrict__ sump,
    const float* __restrict__ f2w, const float* __restrict__ f2b,
    float* __restrict__ sp, float* __restrict__ ssb,
    const float* __restrict__ wih, const float* __restrict__ whh,
    const float* __restrict__ bih, const float* __restrict__ bhh,
    const float* __restrict__ m_ng, const float* __restrict__ m_nb,
    const float* __restrict__ m1w, const float* __restrict__ m1b,
    const float* __restrict__ m2w, const float* __restrict__ m2b,
    float* __restrict__ slots){
  int bs = blockIdx.x, t = threadIdx.x;
  __shared__ float hs[256], u[256], spv[256], hln[256], r1[1024];
  __shared__ float sc[8], s4[4];
  {
    float a=0.f;
    #pragma unroll
    for (int c=0;c<8;c++) a += hvpart[(size_t)(bs*8+c)*256 + t];
    hs[t] = a;
  }
  spv[t] = slots[bs*256+t];
  if (t == 0){
    float A0=0.f;
    for (int c=0;c<8;c++) A0 += sump[bs*8+c];
    sc[0]=A0; sc[1]=A0+1e-8f;
  }
  if (t < 6){
    float mm=0.f;
    for (int c=0;c<8;c++) mm += mompart[(bs*8+c)*6 + t];
    sc[2+t] = mm;
  }
  __syncthreads();
  float A0 = sc[0], denom = sc[1];
  if (t < 3){
    float A1 = sc[2+t], A2 = sc[5+t];
    float p = A1/denom;
    float var = (A2 - 2.f*p*A1 + p*p*A0)/denom + 1e-6f;
    float sv = clampf(sqrtf(var), 0.2f, 5.f);
    sp[bs*3+t] = p; ssb[bs*3+t] = sv;
  }
  {
    float dd = 0.f;
    const float4* fr = (const float4*)(f2w + (size_t)t*256);
    for (int h4=0; h4<64; ++h4){
      float4 w4 = fr[h4];
      dd += hs[h4*4+0]*w4.x + hs[h4*4+1]*w4.y + hs[h4*4+2]*w4.z + hs[h4*4+3]*w4.w;
    }
    u[t] = n2nf((dd + A0*f2b[t])/denom);
  }
  __syncthreads();
  float gi[3], gh[3];
  #pragma unroll 1
  for (int part=0; part<3; ++part){
    int o = part*256 + t;
    const float4* wr = (const float4*)(wih + (size_t)o*256);
    const float4* hr = (const float4*)(whh + (size_t)o*256);
    float si = bih[o], sh = bhh[o];
    for (int d4=0; d4<64; ++d4){
      float4 a4 = wr[d4], b4 = hr[d4];
      si += u[d4*4+0]*a4.x + u[d4*4+1]*a4.y + u[d4*4+2]*a4.z + u[d4*4+3]*a4.w;
      sh += spv[d4*4+0]*b4.x + spv[d4*4+1]*b4.y + spv[d4*4+2]*b4.z + spv[d4*4+3]*b4.w;
    }
    gi[part]=si; gh[part]=sh;
  }
  float rg = sigmoidf(gi[0]+gh[0]);
  float zg = sigmoidf(gi[1]+gh[1]);
  float nn = tanhf(gi[2] + rg*gh[2]);
  float hnew = (1.f-zg)*nn + zg*spv[t];
  float m = blkSum(hnew, s4, t)*(1.f/256.f);
  float dv = hnew - m;
  float var = blkSum(dv*dv, s4, t)*(1.f/256.f);
  hln[t] = dv*(1.f/sqrtf(var+1e-5f))*m_ng[t] + m_nb[t];
  __syncthreads();
  #pragma unroll 1
  for (int oi=0; oi<4; ++oi){
    int o = t*4 + oi;
    const float4* mr = (const float4*)(m1w + (size_t)o*256);
    float s = m1b[o];
    for (int d4=0; d4<64; ++d4){
      float4 a4 = mr[d4];
      s += hln[d4*4+0]*a4.x + hln[d4*4+1]*a4.y + hln[d4*4+2]*a4.z + hln[d4*4+3]*a4.w;
    }
    r1[o] = fmaxf(s, 0.f);
  }
  __syncthreads();
  {
    const float4* mr = (const float4*)(m2w + (size_t)t*1024);
    float s = m2b[t];
    for (int o4=0; o4<256; ++o4){
      float4 a4 = mr[o4];
      s += r1[o4*4+0]*a4.x + r1[o4*4+1]*a4.y + r1[o4*4+2]*a4.z + r1[o4*4+3]*a4.w;
    }
    slots[bs*256+t] = n2nf(hnew + s);
  }
}

__global__ __launch_bounds__(256) void k_attn_out(const float* __restrict__ aun, const float* __restrict__ sump,
                                                  float* __restrict__ outp){
  int g = blockIdx.x*256 + threadIdx.x;
  int bs = g >> 11;
  __shared__ float dsh;
  if (threadIdx.x == 0){
    float s=0.f;
    for (int c=0;c<8;c++) s += sump[bs*8+c];
    dsh = s + 1e-8f;
  }
  __syncthreads();
  outp[g] = aun[g] / dsh;
}

__global__ __launch_bounds__(256) void k_final(const float* __restrict__ slots,
    const float* __restrict__ fw, const float* __restrict__ fb, float* __restrict__ outp){
  int bs = blockIdx.x, t = threadIdx.x;
  __shared__ float sl[256];
  sl[t] = slots[bs*256+t];
  __syncthreads();
  const float4* fr = (const float4*)(fw + (size_t)t*256);
  float s = fb[t];
  for (int d4=0; d4<64; ++d4){
    float4 w4 = fr[d4];
    s += sl[d4*4+0]*w4.x + sl[d4*4+1]*w4.y + sl[d4*4+2]*w4.z + sl[d4*4+3]*w4.w;
  }
  outp[bs*256+t] = s;
}

extern "C" void kernel_launch(void* const* d_in, const int* in_sizes, int n_in,
                              void* d_out, int out_size, void* d_ws, size_t ws_size,
                              hipStream_t stream){
  const float* p_inputs = (const float*)d_in[0];
  const float* p_coords = (const float*)d_in[1];
  const float* p_slotsp = (const float*)d_in[2];
  const float* p_Ss0 = (const float*)d_in[3];
  const float* p_Sp0 = (const float*)d_in[4];
  const float* p_Qw  = (const float*)d_in[5];
  const float* p_Kw  = (const float*)d_in[6];
  const float* p_Vw  = (const float*)d_in[7];
  const float* p_gw  = (const float*)d_in[8];
  const float* p_gb  = (const float*)d_in[9];
  const float* p_f1w = (const float*)d_in[10];
  const float* p_f1b = (const float*)d_in[11];
  const float* p_f2w = (const float*)d_in[12];
  const float* p_f2b = (const float*)d_in[13];
  const float* p_ng  = (const float*)d_in[14];
  const float* p_nb  = (const float*)d_in[15];
  const float* p_wih = (const float*)d_in[16];
  const float* p_whh = (const float*)d_in[17];
  const float* p_bih = (const float*)d_in[18];
  const float* p_bhh = (const float*)d_in[19];
  const float* p_mng = (const float*)d_in[20];
  const float* p_mnb = (const float*)d_in[21];
  const float* p_m1w = (const float*)d_in[22];
  const float* p_m1b = (const float*)d_in[23];
  const float* p_m2w = (const float*)d_in[24];
  const float* p_m2b = (const float*)d_in[25];
  const float* p_i0g = (const float*)d_in[26];
  const float* p_i0b = (const float*)d_in[27];
  const float* p_i1w = (const float*)d_in[28];
  const float* p_i1b = (const float*)d_in[29];
  const float* p_i2w = (const float*)d_in[30];
  const float* p_i2b = (const float*)d_in[31];
  const float* p_i3g = (const float*)d_in[32];
  const float* p_i3b = (const float*)d_in[33];
  const float* p_fw  = (const float*)d_in[34];
  const float* p_fb  = (const float*)d_in[35];

  char* ws = (char*)d_ws;
  size_t off = 0;
  auto alloc = [&](size_t bytes)->char*{
    char* p = ws + off;
    off = (off + bytes + 255) & ~(size_t)255;
    return p;
  };
  short* xln   = (short*)alloc(8192ull*768*2);
  short* h1    = (short*)alloc(8192ull*768*2);
  float* x2    = (float*)alloc(8192ull*256*4);
  short* xenc  = (short*)alloc(8192ull*256*2);
  short* kxb   = (short*)alloc(8192ull*256*2);
  short* vxb   = (short*)alloc(8192ull*256*2);
  short* hvb   = (short*)alloc(32ull*2048*256*2);
  float* dots  = (float*)alloc(32ull*2048*4);
  float* aun   = (float*)alloc(32ull*2048*4);
  float* sump  = (float*)alloc(32*8*4);
  float* hvpart= (float*)alloc(32ull*8*256*4);
  float* mompart=(float*)alloc(32*8*6*4);
  short* i1wb  = (short*)alloc(768ull*768*2);
  short* i2wb  = (short*)alloc(256ull*768*2);
  short* kwb   = (short*)alloc(256ull*256*2);
  short* vwb   = (short*)alloc(256ull*256*2);
  short* f1wb  = (short*)alloc(256ull*256*2);
  short* gwp   = (short*)alloc(256ull*64*2);
  float* slots = (float*)alloc(32*256*4);
  float* qf2   = (float*)alloc(32*256*4);
  float* qbv   = (float*)alloc(32*4);
  float* spb   = (float*)alloc(32*3*4);
  float* ssbuf = (float*)alloc(32*3*4);

  auto cvt = [&](const float* s, short* dst, int n){
    k_convert<<<(n+255)/256, 256, 0, stream>>>(s, dst, n);
  };
  cvt(p_i1w, i1wb, 768*768);
  cvt(p_i2w, i2wb, 256*768);
  cvt(p_Kw,  kwb,  256*256);
  cvt(p_Vw,  vwb,  256*256);
  cvt(p_f1w, f1wb, 256*256);
  k_prep_gwp<<<64,256,0,stream>>>(p_gw, p_gb, gwp);
  k_init<<<32,256,0,stream>>>(p_slotsp, p_Sp0, p_Ss0, slots, spb, ssbuf);

  k_ln768<<<8192,256,0,stream>>>(p_inputs, p_i0g, p_i0b, xln);
  k_gemm<<<dim3(128,6),256,0,stream>>>(xln, i1wb, p_i1b, h1, 768, 768, 1|2|4);
  k_gemm<<<dim3(128,2),256,0,stream>>>(h1, i2wb, p_i2b, x2, 256, 768, 1);
  k_ln256<<<8192,256,0,stream>>>(x2, p_i3g, p_i3b, xenc);
  k_gemm<<<dim3(128,2),256,0,stream>>>(xenc, kwb, nullptr, kxb, 256, 256, 4);
  k_gemm<<<dim3(128,2),256,0,stream>>>(xenc, vwb, nullptr, vxb, 256, 256, 4);

  float* outf = (float*)d_out;
  for (int t=0;t<4;t++){
    k_qprep<<<32,256,0,stream>>>(slots, p_ng, p_nb, p_Qw, p_f2w, p_f2b, qf2, qbv);
    k_isa_a<<<dim3(32,32),256,0,stream>>>(p_coords, spb, ssbuf, gwp, kxb, vxb, f1wb, p_f1b, qf2, qbv, dots, hvb, (t<3)?2:1);
    k_softmax<<<32,256,0,stream>>>(dots, aun, sump);
    if (t < 3){
      k_c1<<<dim3(8,32),256,0,stream>>>(aun, hvb, p_coords, hvpart, mompart);
      k_c2<<<32,256,0,stream>>>(hvpart, mompart, sump, p_f2w, p_f2b, spb, ssbuf,
                                p_wih, p_whh, p_bih, p_bhh, p_mng, p_mnb,
                                p_m1w, p_m1b, p_m2w, p_m2b, slots);
    } else {
      k_attn_out<<<256,256,0,stream>>>(aun, sump, outf + 8192);
    }
  }
  k_final<<<32,256,0,stream>>>(slots, p_fw, p_fb, outf);
}